// Round 1
// 714.185 us; speedup vs baseline: 1.0221x; 1.0221x over previous
//
#include <hip/hip_runtime.h>
#include <hip/hip_bf16.h>
#include <cstdint>
#include <cstddef>

// Problem: RNN-T joint. B=4,T=256,U=64, ENC=DEC=640, INNER=512, VOCAB=2048.
// All inputs fp32; output fp32 (4,256,64,2048).

typedef __attribute__((ext_vector_type(8))) short   short8;   // 8 bf16 (4 VGPRs)
typedef __attribute__((ext_vector_type(4))) float   floatx4;  // MFMA acc

__device__ __forceinline__ short f2bf(float f) {
  union { float f; unsigned u; } v; v.f = f;
  unsigned r = (v.u + 0x7fffu + ((v.u >> 16) & 1u)) >> 16;  // RNE
  return (short)(unsigned short)r;
}

// async global->LDS, 16B per lane (global_load_lds_dwordx4)
__device__ __forceinline__ void async16(const void* g, void* l) {
  __builtin_amdgcn_global_load_lds(
      (const __attribute__((address_space(1))) unsigned int*)g,
      (__attribute__((address_space(3))) unsigned int*)l,
      16, 0, 0);
}

// fp32 -> bf16 bulk convert, 8 elems/thread.
__global__ __launch_bounds__(256)
void f32_to_bf16(const float* __restrict__ in, short* __restrict__ out, int n8)
{
  const int i = blockIdx.x * 256 + threadIdx.x;
  if (i >= n8) return;
  const float4* p = (const float4*)in + 2 * (size_t)i;
  const float4 a = p[0], b = p[1];
  short8 o;
  o[0] = f2bf(a.x); o[1] = f2bf(a.y); o[2] = f2bf(a.z); o[3] = f2bf(a.w);
  o[4] = f2bf(b.x); o[5] = f2bf(b.y); o[6] = f2bf(b.z); o[7] = f2bf(b.w);
  ((short8*)out)[i] = o;
}

// ---------------------------------------------------------------------------
// Pipelined bf16 GEMM: C[m][n] = sum_k A[m][k]*B[n][k] (+ bias[n]).
// BM=128, BN=256, BK=64. 8 waves (2Mx4N), 512 threads, per-wave 64x64 out.
// 3 LDS K-tile buffers (48 KiB each, 144 KiB dynamic), lookahead-2 staging:
//   iter kt: read buf kt%3, stage kt+2 -> buf (kt+2)%3 (disjoint -> race-free),
//   boundary wait = COUNTED s_waitcnt vmcnt(6) (kt+1's 6 loads stay in flight).
// LDS XOR-swizzle (T2): 16B-block index ^= (row&7), applied to BOTH the
//   pre-swizzled global_load_lds source and the ds_read address (rule 21).
// T5: setprio(1) around each 16-MFMA cluster. T1: m204 bijective XCD swizzle.
// Requirements: M%128==0, N%256==0 (grid), K%64==0, K/64>=2.
// ---------------------------------------------------------------------------
#define BUFB 49152   // bytes per K-tile buffer: A 128x64x2 (16K) + B 256x64x2 (32K)

__global__ __launch_bounds__(512, 2)
void gemm_pipe(const short* __restrict__ A, int lda,
               const short* __restrict__ B, int ldb, int bcol,
               float* __restrict__ Cout, int ldc,
               const float* __restrict__ bias, int K, int nbx_sh)
{
  extern __shared__ char lds[];
  const int tid  = threadIdx.x;
  const int lane = tid & 63;
  const int w    = tid >> 6;
  const int wm   = (w >> 2) << 6;   // 0 / 64
  const int wn   = (w & 3) << 6;    // 0 / 64 / 128 / 192

  // XCD-chunk swizzle (m204 bijective): contiguous logical chunk per XCD,
  // so the 2^nbx_sh n-blocks sharing an A(H) panel hit the same L2.
  const int nwg = gridDim.x;
  const int qq = nwg >> 3, rr = nwg & 7;
  const int xcd = blockIdx.x & 7, idx = blockIdx.x >> 3;
  const int wg = (xcd < rr ? xcd * (qq + 1) : rr * (qq + 1) + (xcd - rr) * qq) + idx;
  const int nbx_mask = (1 << nbx_sh) - 1;
  const int m_base = (wg >> nbx_sh) << 7;   // gy*128
  const int n_base = (wg & nbx_mask) << 8;  // gx*256

  // stage source (pre-swizzled global): thread tid covers (row=tid>>3, blk=tid&7)
  // of a 64-row granule; LDS dest is linear tid*16 (gload_lds requirement).
  const int srow = tid >> 3;
  const int sblk = (tid & 7) ^ (srow & 7);
  const short* Asrc = A + (size_t)(m_base + srow) * lda + (sblk << 3);
  const short* Bsrc = B + (size_t)(n_base + srow) * ldb + bcol + (sblk << 3);
  const size_t a64 = (size_t)64 * lda;
  const size_t b64 = (size_t)64 * ldb;
  char* const ldst = lds + tid * 16;

  // fragment-read addressing (swizzled): row&7 == arow&7 for all frags
  const int arow = lane & 15;
  const int q4   = lane >> 4;
  const int s7   = arow & 7;
  const int koff0 = ((q4)     ^ s7) << 4;   // kk=0: blocks 0..3
  const int koff1 = ((q4 + 4) ^ s7) << 4;   // kk=1: blocks 4..7
  const size_t aoff = (size_t)(wm + arow) * 128;
  const size_t boff = 16384 + (size_t)(wn + arow) * 128;

  floatx4 acc[4][4];
#pragma unroll
  for (int i = 0; i < 4; i++)
#pragma unroll
    for (int j = 0; j < 4; j++) acc[i][j] = (floatx4)0.0f;

  const int NT = K >> 6;

  // prologue: stage kt=0 -> buf0, kt=1 -> buf1 (6 granule loads each, in order)
#pragma unroll
  for (int t = 0; t < 2; ++t) {
    const int kb = t << 6;
    char* dA = ldst + t * BUFB;
    char* dB = dA + 16384;
    async16(Asrc + kb,             dA);
    async16(Asrc + kb + a64,       dA + 8192);
    async16(Bsrc + kb,             dB);
    async16(Bsrc + kb + b64,       dB + 8192);
    async16(Bsrc + kb + 2 * b64,   dB + 16384);
    async16(Bsrc + kb + 3 * b64,   dB + 24576);
  }

  int r = 0;
  for (int kt = 0; kt < NT; ++kt) {
    // boundary: kt's 6 loads are the oldest; kt+1's 6 stay in flight (counted).
    if (kt + 1 < NT) asm volatile("s_waitcnt vmcnt(6)" ::: "memory");
    else             asm volatile("s_waitcnt vmcnt(0)" ::: "memory");
    __builtin_amdgcn_s_barrier();
    asm volatile("" ::: "memory");   // pin subsequent ds_reads below barrier

    const char* Ab = lds + r * BUFB + aoff;
    const char* Bb = lds + r * BUFB + boff;
    const int r2 = (r >= 1) ? r - 1 : 2;   // (r+2)%3
    char* dA = ldst + r2 * BUFB;
    char* dB = dA + 16384;
    const int  kb2 = (kt + 2) << 6;
    const bool do_stage = (kt + 2 < NT);

    short8 af[4], bf[4];

    // ---- phase 0 (kk=0): ds_read subtile || stage-issue -> barrier -> MFMA
#pragma unroll
    for (int i = 0; i < 4; i++) af[i] = *(const short8*)(Ab + i * 2048 + koff0);
#pragma unroll
    for (int j = 0; j < 4; j++) bf[j] = *(const short8*)(Bb + j * 2048 + koff0);
    if (do_stage) {
      async16(Asrc + kb2,           dA);
      async16(Asrc + kb2 + a64,     dA + 8192);
      async16(Bsrc + kb2,           dB);
    }
    __builtin_amdgcn_s_barrier();
    asm volatile("s_waitcnt lgkmcnt(0)" ::: "memory");
    __builtin_amdgcn_s_setprio(1);
#pragma unroll
    for (int i = 0; i < 4; i++)
#pragma unroll
      for (int j = 0; j < 4; j++)
        acc[i][j] = __builtin_amdgcn_mfma_f32_16x16x32_bf16(af[i], bf[j], acc[i][j], 0, 0, 0);
    __builtin_amdgcn_s_setprio(0);

    // ---- phase 1 (kk=1)
#pragma unroll
    for (int i = 0; i < 4; i++) af[i] = *(const short8*)(Ab + i * 2048 + koff1);
#pragma unroll
    for (int j = 0; j < 4; j++) bf[j] = *(const short8*)(Bb + j * 2048 + koff1);
    if (do_stage) {
      async16(Bsrc + kb2 + b64,     dB + 8192);
      async16(Bsrc + kb2 + 2 * b64, dB + 16384);
      async16(Bsrc + kb2 + 3 * b64, dB + 24576);
    }
    __builtin_amdgcn_s_barrier();
    asm volatile("s_waitcnt lgkmcnt(0)" ::: "memory");
    __builtin_amdgcn_s_setprio(1);
#pragma unroll
    for (int i = 0; i < 4; i++)
#pragma unroll
      for (int j = 0; j < 4; j++)
        acc[i][j] = __builtin_amdgcn_mfma_f32_16x16x32_bf16(af[i], bf[j], acc[i][j], 0, 0, 0);
    __builtin_amdgcn_s_setprio(0);

    r = (r == 2) ? 0 : r + 1;
  }

  // epilogue: D layout row = quad*4 + reg, col = lane&15 (HW-verified m89/m91)
  const int quad = lane >> 4;
  const int coll = lane & 15;
  float bv[4] = {0.f, 0.f, 0.f, 0.f};
  if (bias) {
#pragma unroll
    for (int j = 0; j < 4; j++) bv[j] = bias[n_base + wn + j * 16 + coll];
  }
#pragma unroll
  for (int i = 0; i < 4; i++) {
#pragma unroll
    for (int rr2 = 0; rr2 < 4; rr2++) {
      const size_t row = (size_t)(m_base + wm + i * 16 + quad * 4 + rr2);
#pragma unroll
      for (int j = 0; j < 4; j++) {
        const size_t off = row * (size_t)ldc + (n_base + wn + j * 16 + coll);
        Cout[off] = acc[i][j][rr2] + bv[j];
      }
    }
  }
}

// H[lm][i] = tanh(Pe[b*256+t][i] + Pd[b*64+u][i] + b1[i]) as bf16,
// global m = m0 + lm, b = m>>14, t = (m>>6)&255, u = m&63. 8 elems/thread.
__global__ __launch_bounds__(256)
void tanh_fuse(const float* __restrict__ Pe, const float* __restrict__ Pd,
               const float* __restrict__ b1, short* __restrict__ H, int m0)
{
  const int idx = blockIdx.x * 256 + threadIdx.x;
  const int lm = idx >> 6;
  const int c = (idx & 63) << 3;
  const int m = m0 + lm;
  const int b = m >> 14;
  const int t = (m >> 6) & 255;
  const int u = m & 63;

  const float* pe = Pe + (size_t)((b << 8) + t) * 512 + c;
  const float* pd = Pd + (size_t)((b << 6) + u) * 512 + c;
  const float4 e0 = *(const float4*)pe;
  const float4 e1 = *(const float4*)(pe + 4);
  const float4 d0 = *(const float4*)pd;
  const float4 d1 = *(const float4*)(pd + 4);
  const float4 g0 = *(const float4*)(b1 + c);
  const float4 g1 = *(const float4*)(b1 + c + 4);

  float x[8] = {e0.x + d0.x + g0.x, e0.y + d0.y + g0.y,
                e0.z + d0.z + g0.z, e0.w + d0.w + g0.w,
                e1.x + d1.x + g1.x, e1.y + d1.y + g1.y,
                e1.z + d1.z + g1.z, e1.w + d1.w + g1.w};
  short8 o;
#pragma unroll
  for (int j = 0; j < 8; j++) {
    const float e  = __expf(2.0f * x[j]);        // inf-safe: tanh -> +/-1
    const float th = 1.0f - 2.0f / (e + 1.0f);
    o[j] = f2bf(th);
  }
  *(short8*)(H + (size_t)lm * 512 + c) = o;
}

extern "C" void kernel_launch(void* const* d_in, const int* in_sizes, int n_in,
                              void* d_out, int out_size, void* d_ws, size_t ws_size,
                              hipStream_t stream)
{
  const float* enc = (const float*)d_in[0];  // (4,256,640)
  const float* dec = (const float*)d_in[1];  // (4,64,640)
  const float* W1  = (const float*)d_in[2];  // (512,1280)
  const float* b1  = (const float*)d_in[3];  // (512,)
  const float* W2  = (const float*)d_in[4];  // (2048,512)
  const float* b2  = (const float*)d_in[5];  // (2048,)
  float* out = (float*)d_out;                // (4,256,64,2048)

  // one-time: allow 144 KiB dynamic LDS for gemm_pipe
  static bool attr_done = false;
  if (!attr_done) {
    hipFuncSetAttribute((const void*)gemm_pipe,
                        hipFuncAttributeMaxDynamicSharedMemorySize, 3 * BUFB);
    attr_done = true;
  }

  // ws layout (256B aligned)
  size_t off = 0;
  auto carve = [&](size_t bytes) -> void* {
    void* p = (char*)d_ws + off;
    off += (bytes + 255) & ~(size_t)255;
    return p;
  };
  short* encb = (short*)carve(1024 * 640 * 2);   // 1.25 MB
  short* decb = (short*)carve(256 * 640 * 2);    // 0.31 MB
  short* W1b  = (short*)carve(512 * 1280 * 2);   // 1.25 MB
  short* W2b  = (short*)carve(2048 * 512 * 2);   // 2 MB
  float* Pe   = (float*)carve(1024 * 512 * 4);   // 2 MB
  float* Pd   = (float*)carve(256 * 512 * 4);    // 0.5 MB
  short* H    = (short*)((char*)d_ws + off);     // up to 64 MB, chunked

  // H chunk rows: what fits, multiple of 128
  const size_t avail = (ws_size > off) ? (ws_size - off) : 0;
  long long rpc = (long long)(avail / (512 * 2));
  rpc = (rpc / 128) * 128;
  if (rpc < 128) rpc = 128;
  if (rpc > 65536) rpc = 65536;

  auto cgrid = [](int n8) { return (unsigned)((n8 + 255) / 256); };
  const int n8_enc = 1024 * 640 / 8;
  const int n8_dec = 256 * 640 / 8;
  const int n8_W1  = 512 * 1280 / 8;
  const int n8_W2  = 2048 * 512 / 8;
  f32_to_bf16<<<cgrid(n8_enc), 256, 0, stream>>>(enc, encb, n8_enc);
  f32_to_bf16<<<cgrid(n8_dec), 256, 0, stream>>>(dec, decb, n8_dec);
  f32_to_bf16<<<cgrid(n8_W1),  256, 0, stream>>>(W1,  W1b,  n8_W1);
  f32_to_bf16<<<cgrid(n8_W2),  256, 0, stream>>>(W2,  W2b,  n8_W2);

  // enc_proj: M=1024, N=512, K=640 (W1 cols [0,640));  nbx=2 (sh=1), nby=8
  gemm_pipe<<<16, 512, 3 * BUFB, stream>>>(encb, 640, W1b, 1280, 0,
                                           Pe, 512, nullptr, 640, 1);
  // dec_proj: M=256, N=512, K=640 (W1 cols [640,1280)); nbx=2, nby=2
  gemm_pipe<<<4, 512, 3 * BUFB, stream>>>(decb, 640, W1b, 1280, 640,
                                          Pd, 512, nullptr, 640, 1);

  // chunked: H = tanh(...) then logits = H @ W2^T + b2
  for (long long m0 = 0; m0 < 65536; m0 += rpc) {
    const long long rows = (65536 - m0 < rpc) ? (65536 - m0) : rpc;
    tanh_fuse<<<(unsigned)(rows / 4), 256, 0, stream>>>(Pe, Pd, b1, H, (int)m0);
    // main GEMM: M=rows, N=2048, K=512; nbx=8 (sh=3), nby=rows/128
    gemm_pipe<<<(unsigned)(8 * (rows / 128)), 512, 3 * BUFB, stream>>>(
        H, 512, W2b, 512, 0, out + (size_t)m0 * 2048, 2048, b2, 512, 3);
  }
}